// Round 1
// 717.757 us; speedup vs baseline: 1.0105x; 1.0105x over previous
//
#include <hip/hip_runtime.h>
#include <cstdint>
#include <cstddef>

// Problem constants (static shapes from the reference)
#define CDIM  1024      // C
#define DTDIM 1024      // D*T
#define MDIM  65536     // B * D * T
#define BDIM  64        // B (batch / sentences)
#define VNUM  50        // valid_num

typedef __attribute__((ext_vector_type(8))) short bf16x8;
typedef __attribute__((ext_vector_type(4))) float f32x4;

__device__ __forceinline__ float bf2f(unsigned int u16) {
  return __uint_as_float(u16 << 16);
}
__device__ __forceinline__ unsigned short f2bf(float x) {
  unsigned int u = __float_as_uint(x);
  u += 0x7fffu + ((u >> 16) & 1u);   // round-to-nearest-even
  return (unsigned short)(u >> 16);
}

// async global -> LDS, 16B per lane; LDS dest is wave-uniform base + lane*16
__device__ __forceinline__ void gload16(const void* g, void* l) {
  __builtin_amdgcn_global_load_lds((const __attribute__((address_space(1))) void*)g,
                                   (__attribute__((address_space(3))) void*)l,
                                   16, 0, 0);
}

// ---------------------------------------------------------------------------
// 1) videos fp32 [b][c][dt] -> At bf16 [b*1024+dt][c]  (64x64 LDS transpose)
//    float4 loads, packed 2xbf16 stores, fused per-(b,dt) row sums
// grid (16 dt-tiles, 16 c-tiles, 64 b), 256 thr
__global__ void k_transpose_videos(const float* __restrict__ vid,
                                   unsigned short* __restrict__ At,
                                   float* __restrict__ vsums) {
  __shared__ float t[64][65];
  const int tid = threadIdx.x;
  const int dt0 = blockIdx.x * 64, c0 = blockIdx.y * 64, b = blockIdx.z;
  const int lc = tid >> 4;          // 0..15 (c-row within pass)
  const int l4 = (tid & 15) * 4;    // dt offset (float4)
  const float* src = vid + ((size_t)b * CDIM + c0) * DTDIM + dt0;
#pragma unroll
  for (int p = 0; p < 4; p++) {
    const int c = p * 16 + lc;
    const float4 f = *reinterpret_cast<const float4*>(&src[(size_t)c * DTDIM + l4]);
    t[c][l4 + 0] = f.x; t[c][l4 + 1] = f.y; t[c][l4 + 2] = f.z; t[c][l4 + 3] = f.w;
  }
  __syncthreads();
  const int dr = tid >> 5;          // 0..7 (dt-row within pass)
  const int cl = tid & 31;          // c-pair index
  unsigned int* dstbase = reinterpret_cast<unsigned int*>(
      At + ((size_t)(b * DTDIM + dt0)) * CDIM + c0);
#pragma unroll
  for (int p = 0; p < 8; p++) {
    const int dt = p * 8 + dr;
    const float a0 = t[2 * cl][dt], a1 = t[2 * cl + 1][dt];
    const unsigned int u = (unsigned int)f2bf(a0) | ((unsigned int)f2bf(a1) << 16);
    dstbase[(size_t)dt * 512 + cl] = u;
    float s = a0 + a1;
    s += __shfl_xor(s, 1);  s += __shfl_xor(s, 2);  s += __shfl_xor(s, 4);
    s += __shfl_xor(s, 8);  s += __shfl_xor(s, 16);
    if (cl == 0) atomicAdd(&vsums[(size_t)b * DTDIM + dt0 + dt], s);
  }
}

// ---------------------------------------------------------------------------
// 2) W_v fp32 [kb][c][f] -> Wt bf16 [kb*256+f][c]
// grid (8 f-tiles, 32 c-tiles, 4 kb), 256 thr
__global__ void k_transpose_W(const float* __restrict__ W,
                              unsigned short* __restrict__ Wt) {
  __shared__ float t[32][33];
  const int tx = threadIdx.x & 31, ty = threadIdx.x >> 5;
  const int f0 = blockIdx.x * 32, c0 = blockIdx.y * 32, kb = blockIdx.z;
  const float* src = W + ((size_t)kb * CDIM + c0) * 256 + f0;
#pragma unroll
  for (int i = 0; i < 4; i++) {
    const int cl = ty + i * 8;
    t[cl][tx] = src[(size_t)cl * 256 + tx];
  }
  __syncthreads();
  unsigned short* dst = Wt + ((size_t)(kb * 256 + f0)) * CDIM + c0;
#pragma unroll
  for (int i = 0; i < 4; i++) {
    const int fl = ty + i * 8;
    dst[(size_t)fl * CDIM + tx] = f2bf(t[tx][fl]);
  }
}

// ---------------------------------------------------------------------------
// 3) per-row fp32 sums of a bf16 [nrows][1024] matrix (one wave per row)
__global__ void k_row_sums(const unsigned short* __restrict__ A,
                           float* __restrict__ out, int nrows) {
  const int wave = threadIdx.x >> 6, lane = threadIdx.x & 63;
  const int row = blockIdx.x * 4 + wave;
  if (row >= nrows) return;
  const unsigned short* r = A + (size_t)row * 1024;
  float s = 0.f;
#pragma unroll
  for (int h = 0; h < 2; h++) {
    const uint4 u = *reinterpret_cast<const uint4*>(r + h * 512 + lane * 8);
    s += bf2f(u.x & 0xffffu) + bf2f(u.x >> 16);
    s += bf2f(u.y & 0xffffu) + bf2f(u.y >> 16);
    s += bf2f(u.z & 0xffffu) + bf2f(u.z >> 16);
    s += bf2f(u.w & 0xffffu) + bf2f(u.w >> 16);
  }
#pragma unroll
  for (int o = 32; o; o >>= 1) s += __shfl_down(s, o);
  if (lane == 0) out[row] = s;
}

// ---------------------------------------------------------------------------
// 4) sentence projection (fp32)
// grid (64 s, 4 j), 256 thr
__global__ void k_scat(const float* __restrict__ sent, const float* __restrict__ Ws,
                       const float* __restrict__ bs, unsigned short* __restrict__ scat,
                       float* __restrict__ snorm2) {
  const int s = blockIdx.x, j = blockIdx.y, tid = threadIdx.x;
  __shared__ float sc[1024];
  __shared__ float red[4];
  float p = 0.f;
#pragma unroll
  for (int q = 0; q < 4; q++) {
    const float x = sent[(size_t)s * 1024 + tid + q * 256];
    sc[tid + q * 256] = x;
    p += x;
  }
#pragma unroll
  for (int o = 32; o; o >>= 1) p += __shfl_down(p, o);
  const int wave = tid >> 6, lane = tid & 63;
  if (lane == 0) red[wave] = p;
  __syncthreads();
  const float mean = (red[0] + red[1] + red[2] + red[3]) * (1.f / 1024.f);
  float acc = 0.f;
  const float* W = Ws + ((size_t)j * 1024) * 256 + tid;
  for (int c = 0; c < 1024; c++) acc += (sc[c] - mean) * W[(size_t)c * 256];
  const int n = j * 256 + tid;
  const float val = acc + bs[n];
  scat[(size_t)s * 1024 + n] = f2bf(val);
  float v2 = val * val;
#pragma unroll
  for (int o = 32; o; o >>= 1) v2 += __shfl_down(v2, o);
  if (lane == 0) atomicAdd(&snorm2[s], v2);
}

// ---------------------------------------------------------------------------
// 5) FUSED GEMM — pipelined rewrite (T3+T4+T5):
//    256-row m-slab per block, 512 thr / 8 waves (4 m-groups x 2 n-groups,
//    64x64 out per wave). Per 128-c n-tile: BK=64 K-loop with double-buffered
//    LDS and COUNTED vmcnt(6) (loads stay in flight across raw s_barriers —
//    vmcnt only drains once per n-tile). Fused epilogue (centering+bias ->
//    bf16 vtile in LDS, ss += val^2) and MFMA2 (P += scat . vtile^T) retained.
//    All XOR swizzles identical to the previous (0-bank-conflict) version.
// LDS: sA dbuf 2x32KB | sB dbuf 2x16KB | stile 16KB | invSn 256B | vn 2KB
//      vtile (256x128 bf16 = 64KB) overlaps the (dead-in-epilogue) sA dbuf.
// grid (256), 512 thr
__global__ __launch_bounds__(512, 2) void k_gemm_fused(
    const unsigned short* __restrict__ At, const unsigned short* __restrict__ Wt,
    const float* __restrict__ vsums, const float* __restrict__ csW,
    const float* __restrict__ bv, const unsigned short* __restrict__ scat,
    const float* __restrict__ snorm2, const int* __restrict__ mask,
    float* __restrict__ sim, float* __restrict__ pm) {
  __shared__ alignas(16) char smem[116992];
  unsigned short* sA    = (unsigned short*)smem;            // 2 x [256x64] bf16
  unsigned short* sB    = (unsigned short*)(smem + 65536);  // 2 x [128x64] bf16
  unsigned short* stile = (unsigned short*)(smem + 98304);  // [64x128] bf16
  float* invSnLds       = (float*)(smem + 114688);          // 64 f32
  float* vnLds          = (float*)(smem + 114944);          // 2 x 256 f32
  unsigned short* vtile = (unsigned short*)smem;            // [256x128] bf16 (epilogue)

  const int tid = threadIdx.x;
  const int wave = tid >> 6, lane = tid & 63;
  const int quad = lane >> 4, l16 = lane & 15;
  const int m0 = blockIdx.x * 256;
  const int wm = (wave & 3) * 64, wn = (wave >> 2) * 64;
  const int r8 = lane >> 3, g8 = lane & 7;   // staging: row-in-instr / col chunk

  if (tid < 64) invSnLds[tid] = 1.f / fmaxf(sqrtf(snorm2[tid]), 1e-8f);

  f32x4 acc2[4][2];
#pragma unroll
  for (int i = 0; i < 4; i++)
#pragma unroll
    for (int j = 0; j < 2; j++) acc2[i][j] = f32x4{0.f, 0.f, 0.f, 0.f};
  float ss[4][4];
#pragma unroll
  for (int i = 0; i < 4; i++)
#pragma unroll
    for (int rr = 0; rr < 4; rr++) ss[i][rr] = 0.f;

  const float inv1024 = 1.f / 1024.f;

#pragma unroll 1
  for (int nt = 0; nt < 8; ++nt) {
    const int n0 = nt * 128;

    // 6 gloads/thread per K-step: A (4) + B (2). Swizzle key row&7 (== r8).
    auto stage_ab = [&](int buf, int kt) {
      const int koff = kt * 64;
      unsigned short* dA = sA + buf * 16384;
      unsigned short* dB = sB + buf * 8192;
#pragma unroll
      for (int ii = 0; ii < 4; ii++) {
        const int q = ii * 8 + wave;
        const int r = q * 8 + r8;
        gload16(At + (size_t)(m0 + r) * CDIM + koff + (g8 ^ r8) * 8, dA + q * 512);
      }
#pragma unroll
      for (int ii = 0; ii < 2; ii++) {
        const int q = ii * 8 + wave;
        const int r = q * 8 + r8;
        gload16(Wt + (size_t)(n0 + r) * CDIM + koff + (g8 ^ r8) * 8, dB + q * 512);
      }
    };

    f32x4 acc[4][4];
#pragma unroll
    for (int i = 0; i < 4; i++)
#pragma unroll
      for (int j = 0; j < 4; j++) acc[i][j] = f32x4{0.f, 0.f, 0.f, 0.f};

    auto compute = [&](int buf) {
      const unsigned short* bA = sA + buf * 16384;
      const unsigned short* bB = sB + buf * 8192;
      __builtin_amdgcn_s_setprio(1);
#pragma unroll
      for (int ks = 0; ks < 2; ks++) {
        const int slot = ((ks * 4 + quad) ^ (l16 & 7)) * 8;
        bf16x8 aF[4], bF[4];
#pragma unroll
        for (int i = 0; i < 4; i++)
          aF[i] = *reinterpret_cast<const bf16x8*>(&bA[(wm + i * 16 + l16) * 64 + slot]);
#pragma unroll
        for (int j = 0; j < 4; j++)
          bF[j] = *reinterpret_cast<const bf16x8*>(&bB[(wn + j * 16 + l16) * 64 + slot]);
#pragma unroll
        for (int i = 0; i < 4; i++)
#pragma unroll
          for (int j = 0; j < 4; j++)
            acc[i][j] = __builtin_amdgcn_mfma_f32_16x16x32_bf16(aF[i], bF[j], acc[i][j], 0, 0, 0);
      }
      __builtin_amdgcn_s_setprio(0);
    };

    // prologue: stage scat chunk (2 loads, needed only at MFMA2) + K-tile 0.
    // vmcnt(6) in phase 0 then also guarantees stile+kt0 (the 8 oldest) landed.
#pragma unroll
    for (int ii = 0; ii < 2; ii++) {
      const int q = ii * 8 + wave;
      const int srow = q * 4 + (lane >> 4);
      const int g = (lane & 15) ^ (srow & 15);
      gload16(scat + (size_t)srow * 1024 + n0 + g * 8, stile + q * 512);
    }
    stage_ab(0, 0);

    int cur = 0;
#pragma unroll 1
    for (int kt = 0; kt < 15; ++kt) {
      stage_ab(cur ^ 1, kt + 1);                        // next tile: stays in flight
      asm volatile("s_waitcnt vmcnt(6)" ::: "memory");  // current tile landed
      __builtin_amdgcn_s_barrier();                     // all waves' parts landed
      asm volatile("" ::: "memory");                    // pin ds_reads below barrier
      compute(cur);
      __builtin_amdgcn_s_barrier();                     // all reads done -> cur re-stageable
      cur ^= 1;
    }
    // tail K-step: nothing left to prefetch, drain.
    asm volatile("s_waitcnt vmcnt(0)" ::: "memory");
    __builtin_amdgcn_s_barrier();
    asm volatile("" ::: "memory");
    compute(cur);
    __syncthreads();   // full fence: epilogue ds_writes below must not hoist

    // epilogue: centering+bias, bf16 into vtile (swizzled [m][c]), ss accumulate
#pragma unroll
    for (int i = 0; i < 4; i++) {
      const int rbase = wm + i * 16 + quad * 4;
      const float4 vs = *reinterpret_cast<const float4*>(&vsums[m0 + rbase]);
      const float mu[4] = {vs.x * inv1024, vs.y * inv1024, vs.z * inv1024, vs.w * inv1024};
#pragma unroll
      for (int j = 0; j < 4; j++) {
        const int c = wn + j * 16 + l16;
        const float cs = csW[n0 + c];
        const float bb = bv[n0 + c];
#pragma unroll
        for (int rr = 0; rr < 4; rr++) {
          const int m = rbase + rr;
          const float val = acc[i][j][rr] - mu[rr] * cs + bb;
          ss[i][rr] += val * val;
          const int slot = (c >> 3) ^ (m & 15);
          vtile[m * 128 + slot * 8 + (c & 7)] = f2bf(val);
        }
      }
    }
    __syncthreads();

    // MFMA2: P[s=64][m=256] += scat_chunk . vtile^T  (wave owns 32 m cols)
#pragma unroll
    for (int ks2 = 0; ks2 < 4; ks2++) {
      const int slot = ((ks2 * 4 + quad) ^ l16) * 8;
      bf16x8 a2[4], b2[2];
#pragma unroll
      for (int i2 = 0; i2 < 4; i2++)
        a2[i2] = *reinterpret_cast<const bf16x8*>(&stile[(i2 * 16 + l16) * 128 + slot]);
#pragma unroll
      for (int j2 = 0; j2 < 2; j2++)
        b2[j2] = *reinterpret_cast<const bf16x8*>(&vtile[(wave * 32 + j2 * 16 + l16) * 128 + slot]);
#pragma unroll
      for (int i2 = 0; i2 < 4; i2++)
#pragma unroll
        for (int j2 = 0; j2 < 2; j2++)
          acc2[i2][j2] = __builtin_amdgcn_mfma_f32_16x16x32_bf16(a2[i2], b2[j2], acc2[i2][j2], 0, 0, 0);
    }
    __syncthreads();   // before next nt overwrites stile / sA / sB
  }

  // row norms: reduce ss over the 16 l16-lanes, publish to LDS (2 halves by wn)
#pragma unroll
  for (int i = 0; i < 4; i++)
#pragma unroll
    for (int rr = 0; rr < 4; rr++) {
      float v = ss[i][rr];
      v += __shfl_xor(v, 1); v += __shfl_xor(v, 2);
      v += __shfl_xor(v, 4); v += __shfl_xor(v, 8);
      if (l16 == 0) vnLds[(wave >> 2) * 256 + wm + i * 16 + quad * 4 + rr] = v;
    }
  __syncthreads();

  // normalize + mask + write sim (and positive_map)
  const int b0 = m0 >> 10;
#pragma unroll
  for (int j2 = 0; j2 < 2; j2++) {
    const int ml = wave * 32 + j2 * 16 + l16;
    const float nv = vnLds[ml] + vnLds[256 + ml];
    const float invVn = 1.f / fmaxf(sqrtf(nv), 1e-8f);
    const int mk = mask[m0 + ml];
#pragma unroll
    for (int i2 = 0; i2 < 4; i2++) {
#pragma unroll
      for (int reg = 0; reg < 4; reg++) {
        const int s = i2 * 16 + quad * 4 + reg;
        float val = acc2[i2][j2][reg] * invVn * invSnLds[s];
        if (mk == 0) val = -__builtin_inff();
        sim[(size_t)s * MDIM + m0 + ml] = val;
        if (s == b0) pm[m0 + ml] = val;
      }
    }
  }
}

// ---------------------------------------------------------------------------
// 7) per-(s,b): top-50, IoU penalty, score — ONE WAVE per (s,b), zero barriers
// grid (1024), 256 thr (4 waves)
__global__ void k_topk(const float* __restrict__ sim, const float* __restrict__ iou,
                       const float* __restrict__ lam, float* __restrict__ scores) {
  const int wave = threadIdx.x >> 6, lane = threadIdx.x & 63;
  const int sb = blockIdx.x * 4 + wave;
  const int s = sb >> 6, b = sb & 63;
  __shared__ float tvs[4][VNUM];
  __shared__ int tis[4][VNUM];

  const float* row = sim + (size_t)s * MDIM + (size_t)b * 1024;
  float v[16];
#pragma unroll
  for (int j = 0; j < 16; j++) v[j] = row[j * 64 + lane];

  for (int k = 0; k < VNUM; k++) {
    float bv = v[0]; int bj = 0;
#pragma unroll
    for (int j = 1; j < 16; j++)
      if (v[j] > bv) { bv = v[j]; bj = j; }
    int bidx = bj * 64 + lane;
#pragma unroll
    for (int o = 1; o < 64; o <<= 1) {
      const float ov = __shfl_xor(bv, o);
      const int oi = __shfl_xor(bidx, o);
      if (ov > bv || (ov == bv && oi < bidx)) { bv = ov; bidx = oi; }
    }
    if (lane == 0) { tvs[wave][k] = bv; tis[wave][k] = bidx; }
    const int wj = bidx >> 6;
    const bool mine = (bidx & 63) == lane;
#pragma unroll
    for (int j = 0; j < 16; j++)
      if (mine && wj == j) v[j] = -__builtin_inff();
  }
  __syncthreads();

  float contrib = 0.f;
  if (lane < VNUM) {
    const int myidx = tis[wave][lane];
    float pen = 0.f;
    for (int l = lane + 1; l < VNUM; l++) {
      const float u = iou[(size_t)tis[wave][l] * 1024 + myidx];
      pen += u * u;
    }
    contrib = tvs[wave][lane] * expf(-pen / lam[0]);
  }
#pragma unroll
  for (int o = 32; o; o >>= 1) contrib += __shfl_down(contrib, o);
  if (lane == 0) scores[s * 64 + b] = contrib * (1.f / VNUM);
}

// ---------------------------------------------------------------------------
// 8) final 64x64 loss reduction
__global__ void k_loss(const float* __restrict__ scores, float* __restrict__ out) {
  __shared__ float S[64 * 64];
  __shared__ float diag[64];
  __shared__ float rmax[64], cmax[64];
  const int tid = threadIdx.x;
#pragma unroll
  for (int q = 0; q < 16; q++) S[tid + q * 256] = scores[tid + q * 256];
  __syncthreads();
  if (tid < 64) diag[tid] = S[tid * 64 + tid];
  __syncthreads();
  if (tid < 64) {
    float rm = 0.f, cm = 0.f;
    for (int x = 0; x < 64; x++) {
      if (x != tid) {
        const float cs = 0.2f + S[tid * 64 + x] - diag[tid];
        rm = fmaxf(rm, fmaxf(cs, 0.f));
        const float ci = 0.2f + S[x * 64 + tid] - diag[tid];
        cm = fmaxf(cm, fmaxf(ci, 0.f));
      }
    }
    rmax[tid] = rm; cmax[tid] = cm;
  }
  __syncthreads();
  if (tid == 0) {
    float L = 0.f;
    for (int t = 0; t < 64; t++) L += rmax[t] + cmax[t];
    out[0] = L * (1.f / 64.f);
  }
}

// ---------------------------------------------------------------------------
extern "C" void kernel_launch(void* const* d_in, const int* in_sizes, int n_in,
                              void* d_out, int out_size, void* d_ws, size_t ws_size,
                              hipStream_t stream) {
  (void)in_sizes; (void)n_in; (void)out_size; (void)ws_size;
  const float* videos = (const float*)d_in[0];
  const float* sent   = (const float*)d_in[1];
  const float* lam    = (const float*)d_in[2];
  const int*   mask   = (const int*)d_in[3];
  const float* iou    = (const float*)d_in[4];
  const float* W_v    = (const float*)d_in[6];
  const float* b_v    = (const float*)d_in[7];
  const float* W_s    = (const float*)d_in[8];
  const float* b_s    = (const float*)d_in[9];
  float* out = (float*)d_out;

  char* ws = (char*)d_ws;
  unsigned short* At   = (unsigned short*)(ws + 0);           // 128 MB
  float* sim           = (float*)(ws + 134217728);            // 16 MB
  unsigned short* Wt   = (unsigned short*)(ws + 150994944);   // 2 MB
  unsigned short* scat = (unsigned short*)(ws + 153092096);   // 128 KB
  float* vsums         = (float*)(ws + 153223168);            // 256 KB
  float* snorm2        = (float*)(ws + 153485312);            // 256 B
  float* csW           = (float*)(ws + 153485568);            // 4 KB
  float* scores        = (float*)(ws + 153489664);            // 16 KB

  // zero vsums + snorm2 (adjacent)
  hipMemsetAsync(vsums, 0, 262144 + 256, stream);

  k_transpose_videos<<<dim3(16, 16, 64), 256, 0, stream>>>(videos, At, vsums);
  k_transpose_W<<<dim3(8, 32, 4), 256, 0, stream>>>(W_v, Wt);
  k_row_sums<<<256, 256, 0, stream>>>(Wt, csW, 1024);
  k_scat<<<dim3(64, 4), 256, 0, stream>>>(sent, W_s, b_s, scat, snorm2);
  k_gemm_fused<<<dim3(256), 512, 0, stream>>>(At, Wt, vsums, csW, b_v, scat,
                                              snorm2, mask, sim, out + 1);
  k_topk<<<dim3(1024), 256, 0, stream>>>(sim, iou, lam, scores);
  k_loss<<<1, 256, 0, stream>>>(scores, out);
}